// Round 1
// baseline (125.953 us; speedup 1.0000x reference)
//
#include <hip/hip_runtime.h>

// Problem constants (from setup_inputs): B=32, H=W=512
#define BATCH 32
#define HW 262144           // 512*512 elements per batch image
#define HW4 65536           // float4 per batch image
#define BLOCKS_PER_BATCH 32 // kernel A: 32 blocks per batch
#define F4_PER_BLOCK 2048   // 65536/32 float4 per block
#define W_IMG 512

// Workspace layout (doubles):
//  [0..31]   sum of output per batch
//  [32..63]  sum of density per batch
//  [64]      global sum of (o-d)^2
//  [65..160] box sums (96 boxes)
#define WS_DOUBLES 161

__device__ __forceinline__ double wave_reduce_d(double v) {
    for (int off = 32; off > 0; off >>= 1)
        v += __shfl_down(v, off, 64);
    return v;
}

// Kernel A: streaming reduction. grid = BATCH*BLOCKS_PER_BATCH blocks, 256 thr.
// Each block handles 2048 consecutive float4 of one batch image.
__global__ __launch_bounds__(256) void main_reduce(const float4* __restrict__ o4,
                                                   const float4* __restrict__ d4,
                                                   double* __restrict__ ws) {
    const int batch = blockIdx.x >> 5;           // /32
    const int blkInBatch = blockIdx.x & 31;
    const size_t base = (size_t)batch * HW4 + (size_t)blkInBatch * F4_PER_BLOCK;

    double so = 0.0, sd = 0.0, ssq = 0.0;
#pragma unroll
    for (int i = 0; i < 8; ++i) {
        size_t idx = base + threadIdx.x + i * 256;
        float4 a = o4[idx];
        float4 b = d4[idx];
        so += (double)a.x + (double)a.y + (double)a.z + (double)a.w;
        sd += (double)b.x + (double)b.y + (double)b.z + (double)b.w;
        double dx = (double)a.x - (double)b.x;
        double dy = (double)a.y - (double)b.y;
        double dz = (double)a.z - (double)b.z;
        double dw = (double)a.w - (double)b.w;
        ssq += dx * dx + dy * dy + dz * dz + dw * dw;
    }

    // wave reduce (wave = 64), then cross-wave via LDS
    so = wave_reduce_d(so);
    sd = wave_reduce_d(sd);
    ssq = wave_reduce_d(ssq);

    __shared__ double smo[4], smd[4], smq[4];
    const int lane = threadIdx.x & 63;
    const int wid = threadIdx.x >> 6;
    if (lane == 0) { smo[wid] = so; smd[wid] = sd; smq[wid] = ssq; }
    __syncthreads();
    if (threadIdx.x == 0) {
        double to = smo[0] + smo[1] + smo[2] + smo[3];
        double td = smd[0] + smd[1] + smd[2] + smd[3];
        double tq = smq[0] + smq[1] + smq[2] + smq[3];
        atomicAdd(&ws[batch], to);
        atomicAdd(&ws[BATCH + batch], td);
        atomicAdd(&ws[2 * BATCH], tq);
    }
}

// Kernel B: box rectangle sums. grid = (16 row-chunks, 96 boxes), 256 thr.
__global__ __launch_bounds__(256) void box_sums(const float* __restrict__ out,
                                                const int* __restrict__ bb,
                                                double* __restrict__ ws_box) {
    const int box = blockIdx.y;       // 0..95
    const int b = box / 3;
    const int* p = bb + box * 4;
    int x1 = min(max(p[0], 0), W_IMG);
    int y1 = min(max(p[1], 0), W_IMG);
    int x2 = min(max(p[2], 0), W_IMG);
    int y2 = min(max(p[3], 0), W_IMG);
    x2 = max(x2, x1);
    y2 = max(y2, y1);

    const float* base = out + (size_t)b * HW;
    double s = 0.0;
    for (int y = y1 + blockIdx.x; y < y2; y += gridDim.x) {
        const float* row = base + (size_t)y * W_IMG;
        for (int x = x1 + threadIdx.x; x < x2; x += 256)
            s += (double)row[x];
    }

    s = wave_reduce_d(s);
    __shared__ double sm[4];
    const int lane = threadIdx.x & 63;
    const int wid = threadIdx.x >> 6;
    if (lane == 0) sm[wid] = s;
    __syncthreads();
    if (threadIdx.x == 0) {
        double t = sm[0] + sm[1] + sm[2] + sm[3];
        if (t != 0.0) atomicAdd(&ws_box[box], t);
    }
}

// Kernel C: combine. 1 block, 128 threads.
__global__ __launch_bounds__(128) void finalize(const double* __restrict__ ws,
                                                const int* __restrict__ nobj,
                                                float* __restrict__ out) {
    __shared__ double sc[128], sm[128];
    const int t = threadIdx.x;
    double c = 0.0, m = 0.0;
    if (t < BATCH) {
        double diff = ws[t] - ws[BATCH + t];
        c = diff * diff;
    }
    if (t < 96) {
        m = 1.0 - ws[65 + t];
        if (m < 0.0) m = 0.0;
    }
    sc[t] = c;
    sm[t] = m;
    __syncthreads();
    for (int s = 64; s > 0; s >>= 1) {
        if (t < s) { sc[t] += sc[t + s]; sm[t] += sm[t + s]; }
        __syncthreads();
    }
    if (t == 0) {
        out[0] = (float)(ws[64] / (double)(*nobj)); // dmap_loss
        out[1] = (float)(sc[0] / (double)BATCH);    // count_loss
        out[2] = (float)sm[0];                      // min_count
    }
}

extern "C" void kernel_launch(void* const* d_in, const int* in_sizes, int n_in,
                              void* d_out, int out_size, void* d_ws, size_t ws_size,
                              hipStream_t stream) {
    const float* output  = (const float*)d_in[0];
    const float* density = (const float*)d_in[1];
    const int*   bboxes  = (const int*)d_in[2];
    const int*   numobj  = (const int*)d_in[3];
    float* out = (float*)d_out;
    double* ws = (double*)d_ws;

    hipMemsetAsync(d_ws, 0, WS_DOUBLES * sizeof(double), stream);

    main_reduce<<<BATCH * BLOCKS_PER_BATCH, 256, 0, stream>>>(
        (const float4*)output, (const float4*)density, ws);

    dim3 gridB(16, 96);
    box_sums<<<gridB, 256, 0, stream>>>(output, bboxes, ws + 65);

    finalize<<<1, 128, 0, stream>>>(ws, numobj, out);
}

// Round 2
// 114.287 us; speedup vs baseline: 1.1021x; 1.1021x over previous
//
#include <hip/hip_runtime.h>

// Problem constants (from setup_inputs): B=32, H=W=512
#define BATCH 32
#define HW 262144           // 512*512 elements per batch image
#define HW4 65536           // float4 per batch image
#define BLOCKS_PER_BATCH 32 // 32 reduce-blocks per batch image
#define F4_PER_BLOCK 2048   // 65536/32 float4 per block
#define W_IMG 512
#define N_REDUCE_BLOCKS 1024       // BATCH * BLOCKS_PER_BATCH
#define N_BOX 96                   // B * 3
#define CHUNKS_PER_BOX 16
#define N_BOX_BLOCKS 1536          // N_BOX * CHUNKS_PER_BOX

// Workspace layout (doubles) — every slot written unconditionally, no init:
//  [0..1023]     per-block sum of output      (slot = batch*32 + sub)
//  [1024..2047]  per-block sum of density
//  [2048..3071]  per-block sum of (o-d)^2
//  [3072..4607]  per-(box,chunk) box partial  (slot = box*16 + chunk)
#define WS_SO   0
#define WS_SD   1024
#define WS_SQ   2048
#define WS_BOX  3072

__device__ __forceinline__ double wave_reduce_d(double v) {
    for (int off = 32; off > 0; off >>= 1)
        v += __shfl_down(v, off, 64);
    return v;
}

// Fused kernel: blocks [0,1024) stream-reduce; blocks [1024,2560) box sums.
// 256 threads per block.
__global__ __launch_bounds__(256) void fused_partials(const float4* __restrict__ o4,
                                                      const float4* __restrict__ d4,
                                                      const float* __restrict__ out_f,
                                                      const int* __restrict__ bb,
                                                      double* __restrict__ ws) {
    const int lane = threadIdx.x & 63;
    const int wid = threadIdx.x >> 6;
    __shared__ double sm0[4], sm1[4], sm2[4];

    if (blockIdx.x < N_REDUCE_BLOCKS) {
        // ---- streaming reduction over output/density ----
        const int blk = blockIdx.x;
        const size_t base = (size_t)blk * F4_PER_BLOCK;

        double so = 0.0, sd = 0.0, ssq = 0.0;
#pragma unroll
        for (int i = 0; i < 8; ++i) {
            size_t idx = base + threadIdx.x + i * 256;
            float4 a = o4[idx];
            float4 b = d4[idx];
            so += (double)a.x + (double)a.y + (double)a.z + (double)a.w;
            sd += (double)b.x + (double)b.y + (double)b.z + (double)b.w;
            double dx = (double)a.x - (double)b.x;
            double dy = (double)a.y - (double)b.y;
            double dz = (double)a.z - (double)b.z;
            double dw = (double)a.w - (double)b.w;
            ssq += dx * dx + dy * dy + dz * dz + dw * dw;
        }

        so = wave_reduce_d(so);
        sd = wave_reduce_d(sd);
        ssq = wave_reduce_d(ssq);
        if (lane == 0) { sm0[wid] = so; sm1[wid] = sd; sm2[wid] = ssq; }
        __syncthreads();
        if (threadIdx.x == 0) {
            ws[WS_SO + blk] = sm0[0] + sm0[1] + sm0[2] + sm0[3];
            ws[WS_SD + blk] = sm1[0] + sm1[1] + sm1[2] + sm1[3];
            ws[WS_SQ + blk] = sm2[0] + sm2[1] + sm2[2] + sm2[3];
        }
    } else {
        // ---- box rectangle partial sums ----
        const int idx = blockIdx.x - N_REDUCE_BLOCKS;   // 0..1535
        const int box = idx >> 4;                       // 0..95
        const int chunk = idx & 15;
        const int b = box / 3;
        const int* p = bb + box * 4;
        int x1 = min(max(p[0], 0), W_IMG);
        int y1 = min(max(p[1], 0), W_IMG);
        int x2 = min(max(p[2], 0), W_IMG);
        int y2 = min(max(p[3], 0), W_IMG);
        x2 = max(x2, x1);
        y2 = max(y2, y1);

        const float* base = out_f + (size_t)b * HW;
        double s = 0.0;
        for (int y = y1 + chunk; y < y2; y += CHUNKS_PER_BOX) {
            const float* row = base + (size_t)y * W_IMG;
            for (int x = x1 + threadIdx.x; x < x2; x += 256)
                s += (double)row[x];
        }

        s = wave_reduce_d(s);
        if (lane == 0) sm0[wid] = s;
        __syncthreads();
        if (threadIdx.x == 0)
            ws[WS_BOX + idx] = sm0[0] + sm0[1] + sm0[2] + sm0[3];
    }
}

// Finalize: 1 block, 1024 threads. Reduces all partial slots.
__global__ __launch_bounds__(1024) void finalize(const double* __restrict__ ws,
                                                 const int* __restrict__ nobj,
                                                 float* __restrict__ out) {
    const int t = threadIdx.x;
    const int lane = t & 63;
    const int wid = t >> 6;

    __shared__ double s_diff[32];  // per-batch (sum_o - sum_d)^2
    __shared__ double s_q[16];     // per-wave ssq partial
    __shared__ double s_m[16];     // per-wave min_count partial

    // count_loss: batch = t/32; its 32 partials are exactly lanes [b*32, b*32+31]
    {
        double so = ws[WS_SO + t];
        double sd = ws[WS_SD + t];
        for (int off = 16; off > 0; off >>= 1) {
            so += __shfl_down(so, off, 32);
            sd += __shfl_down(sd, off, 32);
        }
        if ((t & 31) == 0) {
            double d = so - sd;
            s_diff[t >> 5] = d * d;
        }
    }

    // dmap ssq: one partial per thread
    {
        double q = wave_reduce_d(ws[WS_SQ + t]);
        if (lane == 0) s_q[wid] = q;
    }

    // min_count: box = t/16 for t < 1536; reduce within 16-lane groups
    {
        double m = 0.0;
        if (t < N_BOX_BLOCKS) {
            double bs = ws[WS_BOX + t];
            for (int off = 8; off > 0; off >>= 1)
                bs += __shfl_down(bs, off, 16);
            if ((t & 15) == 0) {
                m = 1.0 - bs;
                if (m < 0.0) m = 0.0;
            }
        }
        m = wave_reduce_d(m);
        if (lane == 0) s_m[wid] = m;
    }

    __syncthreads();
    if (t == 0) {
        double cnt = 0.0;
        for (int i = 0; i < 32; ++i) cnt += s_diff[i];
        double q = 0.0, m = 0.0;
        for (int i = 0; i < 16; ++i) { q += s_q[i]; m += s_m[i]; }
        out[0] = (float)(q / (double)(*nobj));   // dmap_loss
        out[1] = (float)(cnt / (double)BATCH);   // count_loss
        out[2] = (float)m;                       // min_count
    }
}

extern "C" void kernel_launch(void* const* d_in, const int* in_sizes, int n_in,
                              void* d_out, int out_size, void* d_ws, size_t ws_size,
                              hipStream_t stream) {
    const float* output  = (const float*)d_in[0];
    const float* density = (const float*)d_in[1];
    const int*   bboxes  = (const int*)d_in[2];
    const int*   numobj  = (const int*)d_in[3];
    float* out = (float*)d_out;
    double* ws = (double*)d_ws;

    fused_partials<<<N_REDUCE_BLOCKS + N_BOX_BLOCKS, 256, 0, stream>>>(
        (const float4*)output, (const float4*)density, output, bboxes, ws);

    finalize<<<1, 1024, 0, stream>>>(ws, numobj, out);
}

// Round 3
// 102.160 us; speedup vs baseline: 1.2329x; 1.1187x over previous
//
#include <hip/hip_runtime.h>

// Problem constants: B=32, H=W=512
#define BATCH 32
#define HW 262144           // elements per image
#define HW4 65536           // float4 per image
#define W_IMG 512
#define N_BLOCKS 1024       // 32 batches * 32 bands (16 rows each)
#define N_BOX 96            // B * 3

// Workspace layout (doubles) — every slot written unconditionally, no init:
//  [0..1023]     per-block sum of output      (slot = batch*32 + band)
//  [1024..2047]  per-block sum of density
//  [2048..3071]  per-block sum of (o-d)^2
//  [3072..6143]  box partials: slot = box*32 + band  (96 boxes x 32 bands)
#define WS_SO   0
#define WS_SD   1024
#define WS_SQ   2048
#define WS_BOX  3072

__device__ __forceinline__ double wave_reduce_d(double v) {
    for (int off = 32; off > 0; off >>= 1)
        v += __shfl_down(v, off, 64);
    return v;
}

// One kernel: each block streams a 16-row band of one image, computing
// sum(o), sum(d), sum((o-d)^2), and partial sums of the 3 boxes of its batch
// from the data already in registers.
__global__ __launch_bounds__(256) void fused_partials(const float4* __restrict__ o4,
                                                      const float4* __restrict__ d4,
                                                      const int* __restrict__ bb,
                                                      double* __restrict__ ws) {
    const int blk = blockIdx.x;
    const int batch = blk >> 5;
    const int band = blk & 31;                 // rows [band*16, band*16+16)
    const size_t base = (size_t)blk * 2048;    // float4 index
    const int t = threadIdx.x;
    const int col0 = (t & 127) * 4;            // constant per thread across iters
    const int rbase = band * 16 + (t >> 7);    // row at iter i = rbase + 2*i

    // Per-box precompute: column masks (constant per thread) + row range.
    float wm[3][4];
    int by1[3], by2[3];
    bool active[3];
#pragma unroll
    for (int k = 0; k < 3; ++k) {
        const int* p = bb + (batch * 3 + k) * 4;
        int x1 = min(max(p[0], 0), W_IMG);
        int y1 = min(max(p[1], 0), W_IMG);
        int x2 = min(max(p[2], 0), W_IMG);
        int y2 = min(max(p[3], 0), W_IMG);
        x2 = max(x2, x1);
        y2 = max(y2, y1);
        by1[k] = y1; by2[k] = y2;
#pragma unroll
        for (int j = 0; j < 4; ++j) {
            int c = col0 + j;
            wm[k][j] = (c >= x1 && c < x2) ? 1.0f : 0.0f;
        }
        active[k] = (y2 > band * 16) && (y1 < band * 16 + 16);  // block-uniform
    }

    double so = 0.0, sd = 0.0, ssq = 0.0;
    float bxs[3] = {0.0f, 0.0f, 0.0f};   // per-thread box partials (<=32 values in [0,1))

#pragma unroll
    for (int i = 0; i < 8; ++i) {
        size_t idx = base + t + i * 256;
        float4 a = o4[idx];
        float4 b = d4[idx];
        so += (double)a.x + (double)a.y + (double)a.z + (double)a.w;
        sd += (double)b.x + (double)b.y + (double)b.z + (double)b.w;
        double dx = (double)a.x - (double)b.x;
        double dy = (double)a.y - (double)b.y;
        double dz = (double)a.z - (double)b.z;
        double dw = (double)a.w - (double)b.w;
        ssq += dx * dx + dy * dy + dz * dz + dw * dw;

        const int row = rbase + 2 * i;
#pragma unroll
        for (int k = 0; k < 3; ++k) {
            if (active[k]) {
                float rok = (row >= by1[k] && row < by2[k]) ? 1.0f : 0.0f;
                float s = a.x * wm[k][0] + a.y * wm[k][1] + a.z * wm[k][2] + a.w * wm[k][3];
                bxs[k] = fmaf(rok, s, bxs[k]);
            }
        }
    }

    // Block reduction of 6 quantities.
    const int lane = t & 63;
    const int wid = t >> 6;
    double b0 = (double)bxs[0], b1 = (double)bxs[1], b2 = (double)bxs[2];
    so = wave_reduce_d(so);
    sd = wave_reduce_d(sd);
    ssq = wave_reduce_d(ssq);
    b0 = wave_reduce_d(b0);
    b1 = wave_reduce_d(b1);
    b2 = wave_reduce_d(b2);

    __shared__ double sm[6][4];
    if (lane == 0) {
        sm[0][wid] = so; sm[1][wid] = sd; sm[2][wid] = ssq;
        sm[3][wid] = b0; sm[4][wid] = b1; sm[5][wid] = b2;
    }
    __syncthreads();
    if (t == 0) {
        ws[WS_SO + blk] = sm[0][0] + sm[0][1] + sm[0][2] + sm[0][3];
        ws[WS_SD + blk] = sm[1][0] + sm[1][1] + sm[1][2] + sm[1][3];
        ws[WS_SQ + blk] = sm[2][0] + sm[2][1] + sm[2][2] + sm[2][3];
#pragma unroll
        for (int k = 0; k < 3; ++k) {
            double bv = sm[3 + k][0] + sm[3 + k][1] + sm[3 + k][2] + sm[3 + k][3];
            ws[WS_BOX + (batch * 3 + k) * 32 + band] = bv;
        }
    }
}

// Finalize: 1 block, 1024 threads.
__global__ __launch_bounds__(1024) void finalize(const double* __restrict__ ws,
                                                 const int* __restrict__ nobj,
                                                 float* __restrict__ out) {
    const int t = threadIdx.x;
    const int lane = t & 63;
    const int wid = t >> 6;

    __shared__ double s_diff[32];  // per-batch (sum_o - sum_d)^2
    __shared__ double s_q[16];     // per-wave ssq partial
    __shared__ double s_m[16];     // per-wave min_count partial

    // count_loss: batch b = t/32; its 32 band-partials are slots [b*32, b*32+31]
    {
        double so = ws[WS_SO + t];
        double sd = ws[WS_SD + t];
        for (int off = 16; off > 0; off >>= 1) {
            so += __shfl_down(so, off, 32);
            sd += __shfl_down(sd, off, 32);
        }
        if ((t & 31) == 0) {
            double d = so - sd;
            s_diff[t >> 5] = d * d;
        }
    }

    // dmap ssq: one partial per thread
    {
        double q = wave_reduce_d(ws[WS_SQ + t]);
        if (lane == 0) s_q[wid] = q;
    }

    // min_count: 3072 box partials; group of 32 lanes = one box, 3 passes.
    {
        double m = 0.0;
#pragma unroll
        for (int k = 0; k < 3; ++k) {
            double bs = ws[WS_BOX + t + k * 1024];
            for (int off = 16; off > 0; off >>= 1)
                bs += __shfl_down(bs, off, 32);
            if ((t & 31) == 0) {
                double r = 1.0 - bs;
                if (r > 0.0) m += r;
            }
        }
        m = wave_reduce_d(m);
        if (lane == 0) s_m[wid] = m;
    }

    __syncthreads();
    if (t == 0) {
        double cnt = 0.0;
        for (int i = 0; i < 32; ++i) cnt += s_diff[i];
        double q = 0.0, m = 0.0;
        for (int i = 0; i < 16; ++i) { q += s_q[i]; m += s_m[i]; }
        out[0] = (float)(q / (double)(*nobj));   // dmap_loss
        out[1] = (float)(cnt / (double)BATCH);   // count_loss
        out[2] = (float)m;                       // min_count
    }
}

extern "C" void kernel_launch(void* const* d_in, const int* in_sizes, int n_in,
                              void* d_out, int out_size, void* d_ws, size_t ws_size,
                              hipStream_t stream) {
    const float* output  = (const float*)d_in[0];
    const float* density = (const float*)d_in[1];
    const int*   bboxes  = (const int*)d_in[2];
    const int*   numobj  = (const int*)d_in[3];
    float* out = (float*)d_out;
    double* ws = (double*)d_ws;

    fused_partials<<<N_BLOCKS, 256, 0, stream>>>(
        (const float4*)output, (const float4*)density, bboxes, ws);

    finalize<<<1, 1024, 0, stream>>>(ws, numobj, out);
}